// Round 5
// baseline (320.354 us; speedup 1.0000x reference)
//
#include <hip/hip_runtime.h>
#include <hip/hip_bf16.h>

typedef float  float4v __attribute__((ext_vector_type(4)));
typedef short  short8v __attribute__((ext_vector_type(8)));
typedef short  short4v __attribute__((ext_vector_type(4)));
typedef __bf16 bf16x8  __attribute__((ext_vector_type(8)));
typedef float  f32x4   __attribute__((ext_vector_type(4)));
typedef float  f32x16  __attribute__((ext_vector_type(16)));

constexpr int NB = 512, T = 64, DIN = 1024, DOUT = 1024;
constexpr int BM = 128, BN = 128, BK = 64;     // fallback tile
constexpr int BN2 = 256;                       // main-path N tile

// ---- workspace layout (bf16-DMA path) ----
constexpr size_t ABF_BYTES = (size_t)NB * T * DIN * 2;   // 67,108,864
constexpr size_t WN_BYTES  = (size_t)DOUT * DIN * 2;     // 2,097,152
constexpr size_t WS_BF16   = ABF_BYTES + WN_BYTES;       // ~69 MB

__device__ __forceinline__ short f2bf_rne(float x) {
    return __builtin_bit_cast(short, __float2bfloat16(x));
}
__device__ __forceinline__ short f2bf_trunc(float x) {   // exact for {0,1}
    return (short)(__builtin_bit_cast(unsigned int, x) >> 16);
}
__device__ __forceinline__ void load_lds_16B(const void* g, void* l) {
    __builtin_amdgcn_global_load_lds(
        (const __attribute__((address_space(1))) unsigned int*)g,
        (__attribute__((address_space(3))) unsigned int*)l, 16, 0, 0);
}

// ---- prepass: A fp32 (binary) -> bf16 via exact truncation. 8 elems/thread.
__global__ void __launch_bounds__(256)
prep_a_kernel(const float* __restrict__ A, short* __restrict__ Abf) {
    int idx = blockIdx.x * 256 + threadIdx.x;            // 8-elem group
    const float4v* p = (const float4v*)A + (size_t)idx * 2;
    float4v v0 = __builtin_nontemporal_load(p);
    float4v v1 = __builtin_nontemporal_load(p + 1);
    short8v s;
    #pragma unroll
    for (int j = 0; j < 4; j++) {
        s[j]     = f2bf_trunc(v0[j]);
        s[j + 4] = f2bf_trunc(v1[j]);
    }
    *((short8v*)Abf + idx) = s;                          // cached: re-read soon
}

// ---- prepass: Wn = bf16(W * gamma/sqrt(rvar))
__global__ void __launch_bounds__(256)
fold_w_kernel(const float* __restrict__ W, const float* __restrict__ gamma,
              const float* __restrict__ rvar, short* __restrict__ Wn) {
    int idx = blockIdx.x * 256 + threadIdx.x;            // float4 group
    int o = idx >> 8;
    float r = gamma[o] / sqrtf(rvar[o]);
    float4v w = ((const float4v*)W)[idx];
    short4v s;
    #pragma unroll
    for (int j = 0; j < 4; j++) s[j] = f2bf_rne(w[j] * r);
    ((short4v*)Wn)[idx] = s;
}

// ---- main: 128x256 tile, 32x32x16 MFMA, full-DMA staging + IF scan
__global__ void __launch_bounds__(256, 2)
snn_gemm_if_dma2(const short* __restrict__ Abf,  // (N*T, DIN) bf16 {0,1}
                 const short* __restrict__ Wn,   // (DOUT, DIN) bf16, BN-folded
                 const float* __restrict__ bias, const float* __restrict__ gamma,
                 const float* __restrict__ beta, const float* __restrict__ rmean,
                 const float* __restrict__ rvar, float* __restrict__ out) {
    __shared__ __align__(16) char smem[49152];   // A 16K + B 32K; potS union 32K
    __shared__ float bstepS[BN2];
    char* AsS   = smem;                          // 1024 slots x 16B
    char* BsS   = smem + 16384;                  // 2048 slots x 16B
    float* potS = (float*)smem;                  // 64 x 128 fp32 (epilogue)

    const int tid = threadIdx.x;
    const int bs  = blockIdx.x;                  // sample pair; XCD = bs % 8
    const int oB  = blockIdx.y * BN2;

    {   // all 256 threads: one bstep each
        int o = oB + tid;
        float r = gamma[o] / sqrtf(rvar[o]);
        bstepS[tid] = ((bias[o] - rmean[o]) * r + beta[o]) * (1.0f / 64.0f);
    }

    const int lane = tid & 63;
    const int wv   = tid >> 6;
    const int wr   = wv & 1;      // 64-row half == sample within pair
    const int wc   = wv >> 1;     // 128-col half
    const int l31  = lane & 31;
    const int half = lane >> 5;
    const int s7   = lane & 7;

    // staging source byte-offsets: slot s -> row=s>>3, chunk=(s&7)^(row&7)
    int srcA[4], srcB[8];
    #pragma unroll
    for (int i = 0; i < 4; i++) {
        int s = i * 256 + tid, row = s >> 3, ck = (s & 7) ^ (row & 7);
        srcA[i] = row * (DIN * 2) + ck * 16;
    }
    #pragma unroll
    for (int i = 0; i < 8; i++) {
        int s = i * 256 + tid, row = s >> 3, ck = (s & 7) ^ (row & 7);
        srcB[i] = row * (DIN * 2) + ck * 16;
    }
    // fragment LDS offsets: row r -> byte r*128 + ((chunk)^(r&7))*16, r&7==lane&7
    int baseA[2], baseB[4], cx[4];
    #pragma unroll
    for (int mi = 0; mi < 2; mi++) baseA[mi] = (wr * 64 + mi * 32 + l31) * 128;
    #pragma unroll
    for (int ni = 0; ni < 4; ni++) baseB[ni] = (wc * 128 + ni * 32 + l31) * 128;
    #pragma unroll
    for (int ks = 0; ks < 4; ks++) cx[ks] = ((ks * 2 + half) ^ s7) * 16;

    f32x16 acc[2][4] = {};
    const char* Ab = (const char*)(Abf + (size_t)bs * BM * DIN);
    const char* Bb = (const char*)(Wn + (size_t)oB * DIN);

    for (int kb = 0; kb < DIN; kb += BK) {
        __syncthreads();                         // prev tile ds_reads done
        const int kbB = kb * 2;
        #pragma unroll
        for (int i = 0; i < 4; i++)
            load_lds_16B(Ab + srcA[i] + kbB, AsS + (i * 256 + tid) * 16);
        #pragma unroll
        for (int i = 0; i < 8; i++)
            load_lds_16B(Bb + srcB[i] + kbB, BsS + (i * 256 + tid) * 16);
        __syncthreads();                         // staged data visible

        #pragma unroll
        for (int ks = 0; ks < 4; ks++) {
            bf16x8 af[2], bf[4];
            #pragma unroll
            for (int mi = 0; mi < 2; mi++)
                af[mi] = __builtin_bit_cast(bf16x8,
                    *(const short8v*)(AsS + baseA[mi] + cx[ks]));
            #pragma unroll
            for (int ni = 0; ni < 4; ni++)
                bf[ni] = __builtin_bit_cast(bf16x8,
                    *(const short8v*)(BsS + baseB[ni] + cx[ks]));
            #pragma unroll
            for (int mi = 0; mi < 2; mi++)
                #pragma unroll
                for (int ni = 0; ni < 4; ni++)
                    acc[mi][ni] = __builtin_amdgcn_mfma_f32_32x32x16_bf16(
                        af[mi], bf[ni], acc[mi][ni], 0, 0, 0);
        }
    }

    __syncthreads();                             // staging free; potS aliases it

    // epilogue: 4 passes (sample s = wr-half, col-half h = wc)
    #pragma unroll 1
    for (int s = 0; s < 2; s++) {
        #pragma unroll 1
        for (int h = 0; h < 2; h++) {
            if (wr == s && wc == h) {
                #pragma unroll
                for (int mi = 0; mi < 2; mi++)
                    #pragma unroll
                    for (int ni = 0; ni < 4; ni++)
                        #pragma unroll
                        for (int reg = 0; reg < 16; reg++) {
                            int t = mi * 32 + (reg & 3) + 8 * (reg >> 2) + 4 * half;
                            potS[t * 128 + ni * 32 + l31] = acc[mi][ni][reg];
                        }
            }
            __syncthreads();
            if (tid < 128) {
                int n = bs * 2 + s;
                float pot = 0.f, cnt = 0.f;
                const float bst = bstepS[h * 128 + tid];
                float* so = out + (size_t)n * T * DOUT + oB + h * 128 + tid;
                for (int t = 0; t < T; t++) {
                    pot += potS[t * 128 + tid] + bst;
                    float spk = (pot >= 1.0f) ? 1.0f : 0.0f;
                    pot -= spk;
                    cnt += spk;
                    __builtin_nontemporal_store(spk, so + (size_t)t * DOUT);
                }
                __builtin_nontemporal_store(
                    cnt, out + (size_t)NB * T * DOUT + (size_t)n * DOUT + oB + h * 128 + tid);
            }
            __syncthreads();
        }
    }
}

// ===================== fallback (round-2 proven path) =====================

constexpr int LDA_F = 72;
constexpr int A_BYTES_F = BM * LDA_F * 2;
constexpr int SMEM_F = A_BYTES_F + BN * BK * 2;

template <bool PREFOLD>
__global__ void __launch_bounds__(256)
snn_gemm_if(const float* __restrict__ A, const float* __restrict__ W,
            const short* __restrict__ Wn,
            const float* __restrict__ bias, const float* __restrict__ gamma,
            const float* __restrict__ beta, const float* __restrict__ rmean,
            const float* __restrict__ rvar, float* __restrict__ out) {
    __shared__ __align__(16) char smem[SMEM_F];
    __shared__ float ratioS[BN];
    __shared__ float bstepS[BN];
    short* AsS  = (short*)smem;
    short* BsS  = (short*)(smem + A_BYTES_F);
    float* potS = (float*)smem;

    const int tid   = threadIdx.x;
    const int by    = blockIdx.y;
    const int oBase = blockIdx.x * BN;

    if (tid < BN) {
        int o = oBase + tid;
        float r = gamma[o] / sqrtf(rvar[o]);
        ratioS[tid] = r;
        bstepS[tid] = ((bias[o] - rmean[o]) * r + beta[o]) * (1.0f / 64.0f);
    }
    __syncthreads();

    const int lane = tid & 63;
    const int wv   = tid >> 6;
    const int wr   = wv & 1;
    const int wc   = wv >> 1;
    const int l15  = lane & 15;
    const int quad = lane >> 4;

    f32x4 acc[4][4] = {};
    const float* Ab = A + (size_t)by * BM * DIN;

    for (int kb = 0; kb < DIN; kb += BK) {
        float4v av[4][2];
        #pragma unroll
        for (int i = 0; i < 4; i++) {
            int g = i * 256 + tid;
            int r = g >> 3, k8 = g & 7;
            const float4v* p = (const float4v*)(Ab + (size_t)r * DIN + kb + k8 * 8);
            av[i][0] = p[0];
            av[i][1] = p[1];
        }
        float4v bv[4][2];
        if constexpr (!PREFOLD) {
            #pragma unroll
            for (int i = 0; i < 4; i++) {
                int slot = i * 256 + tid;
                int r = slot >> 3, k8 = (slot & 7) ^ (r & 7);
                const float4v* p = (const float4v*)(W + (size_t)(oBase + r) * DIN + kb + k8 * 8);
                bv[i][0] = p[0];
                bv[i][1] = p[1];
            }
        }
        __syncthreads();

        if constexpr (PREFOLD) {
            #pragma unroll
            for (int i = 0; i < 4; i++) {
                int slot = i * 256 + tid;
                int r = slot >> 3, k8 = (slot & 7) ^ (r & 7);
                load_lds_16B(Wn + (size_t)(oBase + r) * DIN + kb + k8 * 8,
                             BsS + (size_t)slot * 8);
            }
        } else {
            #pragma unroll
            for (int i = 0; i < 4; i++) {
                int slot = i * 256 + tid;
                int r = slot >> 3;
                float rt = ratioS[r];
                short8v s;
                #pragma unroll
                for (int j = 0; j < 4; j++) {
                    s[j]     = f2bf_rne(bv[i][0][j] * rt);
                    s[j + 4] = f2bf_rne(bv[i][1][j] * rt);
                }
                *(short8v*)(BsS + (size_t)slot * 8) = s;
            }
        }
        #pragma unroll
        for (int i = 0; i < 4; i++) {
            int g = i * 256 + tid;
            int r = g >> 3, k8 = g & 7;
            short8v s;
            #pragma unroll
            for (int j = 0; j < 4; j++) {
                s[j]     = f2bf_trunc(av[i][0][j]);
                s[j + 4] = f2bf_trunc(av[i][1][j]);
            }
            *(short8v*)(&AsS[r * LDA_F + k8 * 8]) = s;
        }
        __syncthreads();

        #pragma unroll
        for (int ks = 0; ks < 2; ks++) {
            bf16x8 af[4], bfv[4];
            #pragma unroll
            for (int mi = 0; mi < 4; mi++)
                af[mi] = __builtin_bit_cast(bf16x8,
                    *(const short8v*)(&AsS[(wr * 64 + mi * 16 + l15) * LDA_F + ks * 32 + quad * 8]));
            #pragma unroll
            for (int ni = 0; ni < 4; ni++) {
                int row  = wc * 64 + ni * 16 + l15;
                int slot = row * 8 + ((ks * 4 + quad) ^ (l15 & 7));
                bfv[ni] = __builtin_bit_cast(bf16x8, *(const short8v*)(BsS + (size_t)slot * 8));
            }
            #pragma unroll
            for (int mi = 0; mi < 4; mi++)
                #pragma unroll
                for (int ni = 0; ni < 4; ni++)
                    acc[mi][ni] = __builtin_amdgcn_mfma_f32_16x16x32_bf16(
                        af[mi], bfv[ni], acc[mi][ni], 0, 0, 0);
        }
    }

    __syncthreads();

    #pragma unroll 1
    for (int s = 0; s < 2; s++) {
        if (wr == s) {
            #pragma unroll
            for (int mi = 0; mi < 4; mi++)
                #pragma unroll
                for (int ni = 0; ni < 4; ni++)
                    #pragma unroll
                    for (int r = 0; r < 4; r++)
                        potS[(mi * 16 + quad * 4 + r) * BN + wc * 64 + ni * 16 + l15] =
                            acc[mi][ni][r];
        }
        __syncthreads();
        if (tid < BN) {
            int n = by * 2 + s;
            float pot = 0.f, cnt = 0.f;
            const float bst = bstepS[tid];
            float* so = out + (size_t)n * T * DOUT + oBase + tid;
            for (int t = 0; t < T; t++) {
                pot += potS[t * BN + tid] + bst;
                float spk = (pot >= 1.0f) ? 1.0f : 0.0f;
                pot -= spk;
                cnt += spk;
                so[(size_t)t * DOUT] = spk;
            }
            out[(size_t)NB * T * DOUT + (size_t)n * DOUT + oBase + tid] = cnt;
        }
        __syncthreads();
    }
}

extern "C" void kernel_launch(void* const* d_in, const int* in_sizes, int n_in,
                              void* d_out, int out_size, void* d_ws, size_t ws_size,
                              hipStream_t stream) {
    const float* A     = (const float*)d_in[0];
    // d_in[1] (input_features_sc) feeds only the un-returned ANN path — dead.
    const float* W     = (const float*)d_in[2];
    const float* bias  = (const float*)d_in[3];
    const float* gamma = (const float*)d_in[4];
    const float* beta  = (const float*)d_in[5];
    const float* rmean = (const float*)d_in[6];
    const float* rvar  = (const float*)d_in[7];
    float* out = (float*)d_out;

    if (d_ws != nullptr && ws_size >= WS_BF16) {
        short* Abf = (short*)d_ws;
        short* Wn  = (short*)((char*)d_ws + ABF_BYTES);
        prep_a_kernel<<<(NB * T * DIN) / 8 / 256, 256, 0, stream>>>(A, Abf);
        fold_w_kernel<<<DOUT * DIN / 4 / 256, 256, 0, stream>>>(W, gamma, rvar, Wn);
        dim3 grid(NB / 2, DOUT / BN2);  // (256, 4): same-sample blocks -> same XCD
        snn_gemm_if_dma2<<<grid, 256, 0, stream>>>(Abf, Wn, bias, gamma, beta,
                                                   rmean, rvar, out);
    } else if (d_ws != nullptr && ws_size >= WN_BYTES) {
        short* Wn = (short*)d_ws;
        fold_w_kernel<<<DOUT * DIN / 4 / 256, 256, 0, stream>>>(W, gamma, rvar, Wn);
        dim3 grid(DOUT / BN, NB / 2);
        snn_gemm_if<true><<<grid, 256, 0, stream>>>(A, W, Wn, bias, gamma, beta,
                                                    rmean, rvar, out);
    } else {
        dim3 grid(DOUT / BN, NB / 2);
        snn_gemm_if<false><<<grid, 256, 0, stream>>>(A, W, nullptr, bias, gamma, beta,
                                                     rmean, rvar, out);
    }
}